// Round 1
// baseline (2011.848 us; speedup 1.0000x reference)
//
#include <hip/hip_runtime.h>

#define N_NODES 100000
#define N_EDGES 1600000
#define D 64
#define SCAN_BLOCKS ((N_NODES + 255) / 256)  // 391

// ---------- CSR build ----------

__global__ void count_k(const int* __restrict__ dst, int* __restrict__ deg, int e) {
    int i = blockIdx.x * blockDim.x + threadIdx.x;
    if (i < e) atomicAdd(&deg[dst[i]], 1);
}

__global__ void scan1_k(const int* __restrict__ deg, int* __restrict__ partial,
                        int* __restrict__ bsums, int n) {
    __shared__ int sm[256];
    int i = blockIdx.x * 256 + threadIdx.x;
    int v = (i < n) ? deg[i] : 0;
    sm[threadIdx.x] = v;
    __syncthreads();
    for (int off = 1; off < 256; off <<= 1) {
        int t = (threadIdx.x >= off) ? sm[threadIdx.x - off] : 0;
        __syncthreads();
        sm[threadIdx.x] += t;
        __syncthreads();
    }
    if (i < n) partial[i] = sm[threadIdx.x];
    if (threadIdx.x == 255) bsums[blockIdx.x] = sm[255];
}

__global__ void scan2_k(int* __restrict__ bsums, int nb) {
    __shared__ int sm[512];
    int v = (threadIdx.x < nb) ? bsums[threadIdx.x] : 0;
    sm[threadIdx.x] = v;
    __syncthreads();
    for (int off = 1; off < 512; off <<= 1) {
        int t = (threadIdx.x >= off) ? sm[threadIdx.x - off] : 0;
        __syncthreads();
        sm[threadIdx.x] += t;
        __syncthreads();
    }
    if (threadIdx.x < nb) bsums[threadIdx.x] = sm[threadIdx.x];
}

__global__ void scan3_k(const int* __restrict__ partial, const int* __restrict__ deg,
                        const int* __restrict__ bsums, int* __restrict__ row_ptr,
                        int n, int nb) {
    int i = blockIdx.x * blockDim.x + threadIdx.x;
    if (i < n) {
        int base = (blockIdx.x > 0) ? bsums[blockIdx.x - 1] : 0;
        row_ptr[i] = partial[i] - deg[i] + base;  // exclusive prefix
    }
    if (i == 0) row_ptr[n] = bsums[nb - 1];
}

__global__ void fill_k(const int* __restrict__ src, const int* __restrict__ dst,
                       const int* __restrict__ row_ptr, int* __restrict__ cursor,
                       int* __restrict__ adj, int e) {
    int i = blockIdx.x * blockDim.x + threadIdx.x;
    if (i < e) {
        int d = dst[i];
        int p = row_ptr[d] + atomicAdd(&cursor[d], 1);
        adj[p] = src[i];
    }
}

// ---------- aggregation: one wave per node, lane = feature ----------

__global__ void aggregate_k(const float* __restrict__ feat,
                            const int* __restrict__ row_ptr,
                            const int* __restrict__ adj,
                            float* __restrict__ mean_out, int n) {
    int wid = (blockIdx.x * blockDim.x + threadIdx.x) >> 6;
    int lane = threadIdx.x & 63;
    if (wid >= n) return;
    int s0 = row_ptr[wid];
    int s1 = row_ptr[wid + 1];
    float acc = 0.0f;
    for (int j = s0; j < s1; j++) {
        int s = adj[j];
        acc += feat[(size_t)s * D + lane];
    }
    int dg = s1 - s0;
    float inv = 1.0f / (float)(dg > 1 ? dg : 1);
    mean_out[(size_t)wid * D + lane] = acc * inv;
}

// ---------- fused linear: out = mean @ Wl^T + bl + feat @ Wr^T (+ relu) ----------
// lane = output feature f; each lane keeps Wl[f][:] and Wr[f][:] in VGPRs.

__global__ __launch_bounds__(256, 2) void linear_k(
    const float* __restrict__ feat, const float* __restrict__ mean,
    const float* __restrict__ Wl, const float* __restrict__ bl,
    const float* __restrict__ Wr, float* __restrict__ out, int n, int do_relu) {
    int lane = threadIdx.x & 63;
    int wid = (blockIdx.x * blockDim.x + threadIdx.x) >> 6;
    int nw = (gridDim.x * blockDim.x) >> 6;

    float wl[D], wr[D];
#pragma unroll
    for (int k = 0; k < D; k += 4) {
        float4 a = *(const float4*)&Wl[lane * D + k];
        wl[k] = a.x; wl[k + 1] = a.y; wl[k + 2] = a.z; wl[k + 3] = a.w;
        float4 b = *(const float4*)&Wr[lane * D + k];
        wr[k] = b.x; wr[k + 1] = b.y; wr[k + 2] = b.z; wr[k + 3] = b.w;
    }
    float bias = bl[lane];

    for (int node = wid; node < n; node += nw) {
        const float4* mrow = (const float4*)(mean + (size_t)node * D);
        const float4* frow = (const float4*)(feat + (size_t)node * D);
        float acc = bias;
#pragma unroll
        for (int q = 0; q < D / 4; q++) {
            float4 m = mrow[q];
            float4 f = frow[q];
            acc += m.x * wl[4 * q] + m.y * wl[4 * q + 1] + m.z * wl[4 * q + 2] + m.w * wl[4 * q + 3];
            acc += f.x * wr[4 * q] + f.y * wr[4 * q + 1] + f.z * wr[4 * q + 2] + f.w * wr[4 * q + 3];
        }
        if (do_relu) acc = fmaxf(acc, 0.0f);
        out[(size_t)node * D + lane] = acc;
    }
}

extern "C" void kernel_launch(void* const* d_in, const int* in_sizes, int n_in,
                              void* d_out, int out_size, void* d_ws, size_t ws_size,
                              hipStream_t stream) {
    const float* x   = (const float*)d_in[0];
    const int*   ei  = (const int*)d_in[1];   // [2, E]: src then dst
    const float* W1l = (const float*)d_in[2];
    const float* b1l = (const float*)d_in[3];
    const float* W1r = (const float*)d_in[4];
    const float* W2l = (const float*)d_in[5];
    const float* b2l = (const float*)d_in[6];
    const float* W2r = (const float*)d_in[7];
    float* out = (float*)d_out;

    const int* src = ei;
    const int* dst = ei + N_EDGES;

    // workspace layout
    float* agg     = (float*)d_ws;                       // N*D
    float* h       = agg + (size_t)N_NODES * D;          // N*D
    int*   deg     = (int*)(h + (size_t)N_NODES * D);    // N
    int*   row_ptr = deg + N_NODES;                      // N+1
    int*   cursor  = row_ptr + N_NODES + 1;              // N
    int*   partial = cursor + N_NODES;                   // N
    int*   bsums   = partial + N_NODES;                  // 512
    int*   adj     = bsums + 512;                        // E

    hipMemsetAsync(deg, 0, N_NODES * sizeof(int), stream);
    hipMemsetAsync(cursor, 0, N_NODES * sizeof(int), stream);

    int eb = (N_EDGES + 255) / 256;
    count_k<<<eb, 256, 0, stream>>>(dst, deg, N_EDGES);
    scan1_k<<<SCAN_BLOCKS, 256, 0, stream>>>(deg, partial, bsums, N_NODES);
    scan2_k<<<1, 512, 0, stream>>>(bsums, SCAN_BLOCKS);
    scan3_k<<<SCAN_BLOCKS, 256, 0, stream>>>(partial, deg, bsums, row_ptr, N_NODES, SCAN_BLOCKS);
    fill_k<<<eb, 256, 0, stream>>>(src, dst, row_ptr, cursor, adj, N_EDGES);

    int ab = (N_NODES + 3) / 4;  // 4 waves per block, one wave per node
    // layer 1
    aggregate_k<<<ab, 256, 0, stream>>>(x, row_ptr, adj, agg, N_NODES);
    linear_k<<<512, 256, 0, stream>>>(x, agg, W1l, b1l, W1r, h, N_NODES, 1);
    // layer 2
    aggregate_k<<<ab, 256, 0, stream>>>(h, row_ptr, adj, agg, N_NODES);
    linear_k<<<512, 256, 0, stream>>>(h, agg, W2l, b2l, W2r, out, N_NODES, 0);
}

// Round 2
// 725.498 us; speedup vs baseline: 2.7731x; 2.7731x over previous
//
#include <hip/hip_runtime.h>

#define N_NODES 100000
#define N_EDGES 1600000
#define D 64
#define SCAN_BLOCKS ((N_NODES + 255) / 256)  // 391

// ---------- CSR build ----------

__global__ void count_k(const int* __restrict__ dst, int* __restrict__ deg, int e) {
    int i = blockIdx.x * blockDim.x + threadIdx.x;
    if (i < e) atomicAdd(&deg[dst[i]], 1);
}

__global__ void scan1_k(const int* __restrict__ deg, int* __restrict__ partial,
                        int* __restrict__ bsums, int n) {
    __shared__ int sm[256];
    int i = blockIdx.x * 256 + threadIdx.x;
    int v = (i < n) ? deg[i] : 0;
    sm[threadIdx.x] = v;
    __syncthreads();
    for (int off = 1; off < 256; off <<= 1) {
        int t = (threadIdx.x >= off) ? sm[threadIdx.x - off] : 0;
        __syncthreads();
        sm[threadIdx.x] += t;
        __syncthreads();
    }
    if (i < n) partial[i] = sm[threadIdx.x];
    if (threadIdx.x == 255) bsums[blockIdx.x] = sm[255];
}

__global__ void scan2_k(int* __restrict__ bsums, int nb) {
    __shared__ int sm[512];
    int v = (threadIdx.x < nb) ? bsums[threadIdx.x] : 0;
    sm[threadIdx.x] = v;
    __syncthreads();
    for (int off = 1; off < 512; off <<= 1) {
        int t = (threadIdx.x >= off) ? sm[threadIdx.x - off] : 0;
        __syncthreads();
        sm[threadIdx.x] += t;
        __syncthreads();
    }
    if (threadIdx.x < nb) bsums[threadIdx.x] = sm[threadIdx.x];
}

__global__ void scan3_k(const int* __restrict__ partial, const int* __restrict__ deg,
                        const int* __restrict__ bsums, int* __restrict__ row_ptr,
                        int n, int nb) {
    int i = blockIdx.x * blockDim.x + threadIdx.x;
    if (i < n) {
        int base = (blockIdx.x > 0) ? bsums[blockIdx.x - 1] : 0;
        row_ptr[i] = partial[i] - deg[i] + base;  // exclusive prefix
    }
    if (i == 0) row_ptr[n] = bsums[nb - 1];
}

__global__ void fill_k(const int* __restrict__ src, const int* __restrict__ dst,
                       const int* __restrict__ row_ptr, int* __restrict__ cursor,
                       int* __restrict__ adj, int e) {
    int i = blockIdx.x * blockDim.x + threadIdx.x;
    if (i < e) {
        int d = dst[i];
        int p = row_ptr[d] + atomicAdd(&cursor[d], 1);
        adj[p] = src[i];
    }
}

// ---------- aggregation: one wave per node, lane = feature ----------
// Unrolled by 4: 4 independent row-gathers in flight per iteration.

__global__ void aggregate_k(const float* __restrict__ feat,
                            const int* __restrict__ row_ptr,
                            const int* __restrict__ adj,
                            float* __restrict__ mean_out, int n) {
    int wid = (blockIdx.x * blockDim.x + threadIdx.x) >> 6;
    int lane = threadIdx.x & 63;
    if (wid >= n) return;
    int s0 = row_ptr[wid];
    int s1 = row_ptr[wid + 1];
    float a0 = 0.0f, a1 = 0.0f, a2 = 0.0f, a3 = 0.0f;
    int j = s0;
    for (; j + 3 < s1; j += 4) {
        int e0 = adj[j], e1 = adj[j + 1], e2 = adj[j + 2], e3 = adj[j + 3];
        a0 += feat[(size_t)e0 * D + lane];
        a1 += feat[(size_t)e1 * D + lane];
        a2 += feat[(size_t)e2 * D + lane];
        a3 += feat[(size_t)e3 * D + lane];
    }
    for (; j < s1; j++) a0 += feat[(size_t)adj[j] * D + lane];
    float acc = (a0 + a1) + (a2 + a3);
    int dg = s1 - s0;
    float inv = 1.0f / (float)(dg > 1 ? dg : 1);
    mean_out[(size_t)wid * D + lane] = acc * inv;
}

// ---------- fused linear: out = mean @ Wl^T + bl + feat @ Wr^T (+ relu) ----------
// lane = output feature f; each lane keeps Wl[f][:] and Wr[f][:] in VGPRs
// (32 float4 fragments = 128 VGPRs of weights). __launch_bounds__(256,1)
// caps VGPRs at 512 so the weight fragments MUST NOT spill (round-1 spill at
// 128-VGPR cap cost 10x over-fetch). 4 accumulators break the FMA chain.

__global__ __launch_bounds__(256, 1) void linear_k(
    const float* __restrict__ feat, const float* __restrict__ mean,
    const float* __restrict__ Wl, const float* __restrict__ bl,
    const float* __restrict__ Wr, float* __restrict__ out, int n, int do_relu) {
    int lane = threadIdx.x & 63;
    int wid = (blockIdx.x * blockDim.x + threadIdx.x) >> 6;
    int nw = (gridDim.x * blockDim.x) >> 6;

    float4 wl4[16], wr4[16];
    const float4* Wl4 = (const float4*)Wl;
    const float4* Wr4 = (const float4*)Wr;
#pragma unroll
    for (int q = 0; q < 16; q++) {
        wl4[q] = Wl4[lane * 16 + q];
        wr4[q] = Wr4[lane * 16 + q];
    }
    float bias = bl[lane];

    for (int node = wid; node < n; node += nw) {
        const float4* mrow = (const float4*)(mean + (size_t)node * D);
        const float4* frow = (const float4*)(feat + (size_t)node * D);
        float a0 = bias, a1 = 0.0f, a2 = 0.0f, a3 = 0.0f;
#pragma unroll
        for (int q = 0; q < 16; q++) {
            float4 m = mrow[q];
            a0 += m.x * wl4[q].x;
            a1 += m.y * wl4[q].y;
            a2 += m.z * wl4[q].z;
            a3 += m.w * wl4[q].w;
            float4 f = frow[q];
            a0 += f.x * wr4[q].x;
            a1 += f.y * wr4[q].y;
            a2 += f.z * wr4[q].z;
            a3 += f.w * wr4[q].w;
        }
        float acc = (a0 + a1) + (a2 + a3);
        if (do_relu) acc = fmaxf(acc, 0.0f);
        out[(size_t)node * D + lane] = acc;
    }
}

extern "C" void kernel_launch(void* const* d_in, const int* in_sizes, int n_in,
                              void* d_out, int out_size, void* d_ws, size_t ws_size,
                              hipStream_t stream) {
    const float* x   = (const float*)d_in[0];
    const int*   ei  = (const int*)d_in[1];   // [2, E]: src then dst
    const float* W1l = (const float*)d_in[2];
    const float* b1l = (const float*)d_in[3];
    const float* W1r = (const float*)d_in[4];
    const float* W2l = (const float*)d_in[5];
    const float* b2l = (const float*)d_in[6];
    const float* W2r = (const float*)d_in[7];
    float* out = (float*)d_out;

    const int* src = ei;
    const int* dst = ei + N_EDGES;

    // workspace layout
    float* agg     = (float*)d_ws;                       // N*D
    float* h       = agg + (size_t)N_NODES * D;          // N*D
    int*   deg     = (int*)(h + (size_t)N_NODES * D);    // N
    int*   row_ptr = deg + N_NODES;                      // N+1
    int*   cursor  = row_ptr + N_NODES + 1;              // N
    int*   partial = cursor + N_NODES;                   // N
    int*   bsums   = partial + N_NODES;                  // 512
    int*   adj     = bsums + 512;                        // E

    hipMemsetAsync(deg, 0, N_NODES * sizeof(int), stream);
    hipMemsetAsync(cursor, 0, N_NODES * sizeof(int), stream);

    int eb = (N_EDGES + 255) / 256;
    count_k<<<eb, 256, 0, stream>>>(dst, deg, N_EDGES);
    scan1_k<<<SCAN_BLOCKS, 256, 0, stream>>>(deg, partial, bsums, N_NODES);
    scan2_k<<<1, 512, 0, stream>>>(bsums, SCAN_BLOCKS);
    scan3_k<<<SCAN_BLOCKS, 256, 0, stream>>>(partial, deg, bsums, row_ptr, N_NODES, SCAN_BLOCKS);
    fill_k<<<eb, 256, 0, stream>>>(src, dst, row_ptr, cursor, adj, N_EDGES);

    int ab = (N_NODES + 3) / 4;  // 4 waves per block, one wave per node
    // layer 1
    aggregate_k<<<ab, 256, 0, stream>>>(x, row_ptr, adj, agg, N_NODES);
    linear_k<<<1024, 256, 0, stream>>>(x, agg, W1l, b1l, W1r, h, N_NODES, 1);
    // layer 2
    aggregate_k<<<ab, 256, 0, stream>>>(h, row_ptr, adj, agg, N_NODES);
    linear_k<<<1024, 256, 0, stream>>>(h, agg, W2l, b2l, W2r, out, N_NODES, 0);
}

// Round 3
// 443.971 us; speedup vs baseline: 4.5315x; 1.6341x over previous
//
#include <hip/hip_runtime.h>

#define N_NODES 100000
#define N_EDGES 1600000
#define D 64
#define SCAN_BLOCKS ((N_NODES + 255) / 256)  // 391

// ---------- CSR build ----------

__global__ void count_k(const int* __restrict__ dst, int* __restrict__ deg, int e) {
    int i = blockIdx.x * blockDim.x + threadIdx.x;
    if (i < e) atomicAdd(&deg[dst[i]], 1);
}

__global__ void scan1_k(const int* __restrict__ deg, int* __restrict__ partial,
                        int* __restrict__ bsums, int n) {
    __shared__ int sm[256];
    int i = blockIdx.x * 256 + threadIdx.x;
    int v = (i < n) ? deg[i] : 0;
    sm[threadIdx.x] = v;
    __syncthreads();
    for (int off = 1; off < 256; off <<= 1) {
        int t = (threadIdx.x >= off) ? sm[threadIdx.x - off] : 0;
        __syncthreads();
        sm[threadIdx.x] += t;
        __syncthreads();
    }
    if (i < n) partial[i] = sm[threadIdx.x];
    if (threadIdx.x == 255) bsums[blockIdx.x] = sm[255];
}

__global__ void scan2_k(int* __restrict__ bsums, int nb) {
    __shared__ int sm[512];
    int v = (threadIdx.x < nb) ? bsums[threadIdx.x] : 0;
    sm[threadIdx.x] = v;
    __syncthreads();
    for (int off = 1; off < 512; off <<= 1) {
        int t = (threadIdx.x >= off) ? sm[threadIdx.x - off] : 0;
        __syncthreads();
        sm[threadIdx.x] += t;
        __syncthreads();
    }
    if (threadIdx.x < nb) bsums[threadIdx.x] = sm[threadIdx.x];
}

__global__ void scan3_k(const int* __restrict__ partial, const int* __restrict__ deg,
                        const int* __restrict__ bsums, int* __restrict__ row_ptr,
                        int n, int nb) {
    int i = blockIdx.x * blockDim.x + threadIdx.x;
    if (i < n) {
        int base = (blockIdx.x > 0) ? bsums[blockIdx.x - 1] : 0;
        row_ptr[i] = partial[i] - deg[i] + base;  // exclusive prefix
    }
    if (i == 0) row_ptr[n] = bsums[nb - 1];
}

__global__ void fill_k(const int* __restrict__ src, const int* __restrict__ dst,
                       const int* __restrict__ row_ptr, int* __restrict__ cursor,
                       int* __restrict__ adj, int e) {
    int i = blockIdx.x * blockDim.x + threadIdx.x;
    if (i < e) {
        int d = dst[i];
        int p = row_ptr[d] + atomicAdd(&cursor[d], 1);
        adj[p] = src[i];
    }
}

// ---------- aggregation: one wave per node ----------
// lane quarter q = lane/16 handles edge slots (base+q, base+q+4); fp = lane%16
// covers features 4*fp..4*fp+3 as float4. One dwordx4 instr gathers a full
// 256B row per 16-lane quarter (4 rows per wave-instr). Cross-quarter sum via
// __shfl_xor(16/32), lanes 0-15 store the scaled mean row.

__global__ void aggregate_k(const float* __restrict__ feat,
                            const int* __restrict__ row_ptr,
                            const int* __restrict__ adj,
                            float* __restrict__ mean_out, int n) {
    int wid = (blockIdx.x * blockDim.x + threadIdx.x) >> 6;
    if (wid >= n) return;
    int lane = threadIdx.x & 63;
    int q = lane >> 4;
    int fp = lane & 15;

    int s0 = row_ptr[wid];
    int s1 = row_ptr[wid + 1];

    float ax0 = 0.f, ay0 = 0.f, az0 = 0.f, aw0 = 0.f;
    float ax1 = 0.f, ay1 = 0.f, az1 = 0.f, aw1 = 0.f;

    int j = s0 + q;
    for (; j + 4 < s1; j += 8) {
        int sa = adj[j];
        int sb = adj[j + 4];
        float4 va = *(const float4*)&feat[(size_t)sa * D + 4 * fp];
        float4 vb = *(const float4*)&feat[(size_t)sb * D + 4 * fp];
        ax0 += va.x; ay0 += va.y; az0 += va.z; aw0 += va.w;
        ax1 += vb.x; ay1 += vb.y; az1 += vb.z; aw1 += vb.w;
    }
    if (j < s1) {
        int sa = adj[j];
        float4 va = *(const float4*)&feat[(size_t)sa * D + 4 * fp];
        ax0 += va.x; ay0 += va.y; az0 += va.z; aw0 += va.w;
    }
    float rx = ax0 + ax1, ry = ay0 + ay1, rz = az0 + az1, rw = aw0 + aw1;

    // reduce across the 4 quarters
    rx += __shfl_xor(rx, 16); ry += __shfl_xor(ry, 16);
    rz += __shfl_xor(rz, 16); rw += __shfl_xor(rw, 16);
    rx += __shfl_xor(rx, 32); ry += __shfl_xor(ry, 32);
    rz += __shfl_xor(rz, 32); rw += __shfl_xor(rw, 32);

    if (q == 0) {
        int dg = s1 - s0;
        float inv = 1.0f / (float)(dg > 1 ? dg : 1);
        float4 o;
        o.x = rx * inv; o.y = ry * inv; o.z = rz * inv; o.w = rw * inv;
        *(float4*)&mean_out[(size_t)wid * D + 4 * fp] = o;
    }
}

// ---------- linear as register-tiled GEMM ----------
// C[n][f] = sum_k mean[n][k]*Wl[f][k] + feat[n][k]*Wr[f][k] + bl[f] (+relu)
// Block: 128 nodes x 64 features, 256 threads, thread = 8 nodes x 4 features.
// Ws[k][f] (k<64: Wl, k>=64: Wr) staged once; Xs[k][node] per 32-k chunk.
// Strides 68/132 keep all LDS accesses broadcast or 2-way (free).

#define TN 128
#define KC 32
#define XS_STR 132
#define WS_STR 68

__global__ void linear_gemm_k(const float* __restrict__ mean,
                              const float* __restrict__ feat,
                              const float* __restrict__ Wl,
                              const float* __restrict__ Wr,
                              const float* __restrict__ bl,
                              float* __restrict__ out, int n, int do_relu) {
    __shared__ float Ws[128 * WS_STR];
    __shared__ float Xs[KC * XS_STR];

    int t = threadIdx.x;
    int tx = t & 15;   // feature group: f0 = 4*tx
    int ty = t >> 4;   // node group:    n0 = 8*ty
    int nb = blockIdx.x * TN;

    // stage W once: Ws[k][f]; lane-linear f => conflict-free LDS writes
    {
        int f = t & 63;
#pragma unroll
        for (int r = 0; r < 4; r++) {
            int kq = (t >> 6) + 4 * r;  // 0..15
            float4 a = *(const float4*)&Wl[f * 64 + 4 * kq];
            Ws[(4 * kq + 0) * WS_STR + f] = a.x;
            Ws[(4 * kq + 1) * WS_STR + f] = a.y;
            Ws[(4 * kq + 2) * WS_STR + f] = a.z;
            Ws[(4 * kq + 3) * WS_STR + f] = a.w;
            float4 b = *(const float4*)&Wr[f * 64 + 4 * kq];
            Ws[(64 + 4 * kq + 0) * WS_STR + f] = b.x;
            Ws[(64 + 4 * kq + 1) * WS_STR + f] = b.y;
            Ws[(64 + 4 * kq + 2) * WS_STR + f] = b.z;
            Ws[(64 + 4 * kq + 3) * WS_STR + f] = b.w;
        }
    }

    float acc[8][4];
#pragma unroll
    for (int i = 0; i < 8; i++)
#pragma unroll
        for (int jj = 0; jj < 4; jj++) acc[i][jj] = 0.0f;

    int kq8 = t & 7;      // staging: k-quad within chunk
    int nd0 = t >> 3;     // staging: node (0..31), +32 per round

#pragma unroll
    for (int c = 0; c < 4; c++) {
        const float* srcp = (c < 2) ? mean : feat;
        int kb = (c & 1) * KC;  // k offset within source row

        __syncthreads();  // protect Xs from previous chunk's readers
#pragma unroll
        for (int r = 0; r < 4; r++) {
            int node = nd0 + 32 * r;
            int g = nb + node;
            if (g >= n) g = n - 1;  // safe clamp; padding rows never stored
            float4 v = *(const float4*)&srcp[(size_t)g * D + kb + 4 * kq8];
            Xs[(4 * kq8 + 0) * XS_STR + node] = v.x;
            Xs[(4 * kq8 + 1) * XS_STR + node] = v.y;
            Xs[(4 * kq8 + 2) * XS_STR + node] = v.z;
            Xs[(4 * kq8 + 3) * XS_STR + node] = v.w;
        }
        __syncthreads();

        int kws = c * KC;  // row offset into Ws
#pragma unroll 4
        for (int kk = 0; kk < KC; kk++) {
            float4 w = *(const float4*)&Ws[(kws + kk) * WS_STR + 4 * tx];
            float4 x0 = *(const float4*)&Xs[kk * XS_STR + 8 * ty];
            float4 x1 = *(const float4*)&Xs[kk * XS_STR + 8 * ty + 4];
            float xr[8] = {x0.x, x0.y, x0.z, x0.w, x1.x, x1.y, x1.z, x1.w};
            float wv[4] = {w.x, w.y, w.z, w.w};
#pragma unroll
            for (int i = 0; i < 8; i++)
#pragma unroll
                for (int jj = 0; jj < 4; jj++) acc[i][jj] += xr[i] * wv[jj];
        }
    }

    float4 bias = *(const float4*)&bl[4 * tx];
#pragma unroll
    for (int i = 0; i < 8; i++) {
        int g = nb + 8 * ty + i;
        if (g < n) {
            float4 o;
            o.x = acc[i][0] + bias.x;
            o.y = acc[i][1] + bias.y;
            o.z = acc[i][2] + bias.z;
            o.w = acc[i][3] + bias.w;
            if (do_relu) {
                o.x = fmaxf(o.x, 0.f); o.y = fmaxf(o.y, 0.f);
                o.z = fmaxf(o.z, 0.f); o.w = fmaxf(o.w, 0.f);
            }
            *(float4*)&out[(size_t)g * D + 4 * tx] = o;
        }
    }
}

extern "C" void kernel_launch(void* const* d_in, const int* in_sizes, int n_in,
                              void* d_out, int out_size, void* d_ws, size_t ws_size,
                              hipStream_t stream) {
    const float* x   = (const float*)d_in[0];
    const int*   ei  = (const int*)d_in[1];   // [2, E]: src then dst
    const float* W1l = (const float*)d_in[2];
    const float* b1l = (const float*)d_in[3];
    const float* W1r = (const float*)d_in[4];
    const float* W2l = (const float*)d_in[5];
    const float* b2l = (const float*)d_in[6];
    const float* W2r = (const float*)d_in[7];
    float* out = (float*)d_out;

    const int* src = ei;
    const int* dst = ei + N_EDGES;

    // workspace layout
    float* agg     = (float*)d_ws;                       // N*D
    float* h       = agg + (size_t)N_NODES * D;          // N*D
    int*   deg     = (int*)(h + (size_t)N_NODES * D);    // N
    int*   row_ptr = deg + N_NODES;                      // N+1
    int*   cursor  = row_ptr + N_NODES + 1;              // N
    int*   partial = cursor + N_NODES;                   // N
    int*   bsums   = partial + N_NODES;                  // 512
    int*   adj     = bsums + 512;                        // E

    hipMemsetAsync(deg, 0, N_NODES * sizeof(int), stream);
    hipMemsetAsync(cursor, 0, N_NODES * sizeof(int), stream);

    int eb = (N_EDGES + 255) / 256;
    count_k<<<eb, 256, 0, stream>>>(dst, deg, N_EDGES);
    scan1_k<<<SCAN_BLOCKS, 256, 0, stream>>>(deg, partial, bsums, N_NODES);
    scan2_k<<<1, 512, 0, stream>>>(bsums, SCAN_BLOCKS);
    scan3_k<<<SCAN_BLOCKS, 256, 0, stream>>>(partial, deg, bsums, row_ptr, N_NODES, SCAN_BLOCKS);
    fill_k<<<eb, 256, 0, stream>>>(src, dst, row_ptr, cursor, adj, N_EDGES);

    int ab = (N_NODES + 3) / 4;          // one wave per node, 4 waves/block
    int gb = (N_NODES + TN - 1) / TN;    // 782 GEMM blocks

    // layer 1
    aggregate_k<<<ab, 256, 0, stream>>>(x, row_ptr, adj, agg, N_NODES);
    linear_gemm_k<<<gb, 256, 0, stream>>>(agg, x, W1l, W1r, b1l, h, N_NODES, 1);
    // layer 2
    aggregate_k<<<ab, 256, 0, stream>>>(h, row_ptr, adj, agg, N_NODES);
    linear_gemm_k<<<gb, 256, 0, stream>>>(agg, h, W2l, W2r, b2l, out, N_NODES, 0);
}